// Round 2
// baseline (2367.733 us; speedup 1.0000x reference)
//
#include <hip/hip_runtime.h>

#define NNODES 100000
#define DDIM   512
#define NCLS   40
#define KPAD   56   // LDS bf16 row stride: 112B = 16B-aligned rows, 2-way bank aliasing (free, m136)

typedef unsigned short bf16_t;
typedef short bf16x8 __attribute__((ext_vector_type(8)));   // gfx950 bf16 MFMA frag (guide §3)
typedef float f32x4  __attribute__((ext_vector_type(4)));
typedef unsigned int u32x4 __attribute__((ext_vector_type(4)));  // for __builtin_nontemporal_store

__device__ __forceinline__ float bf2f(unsigned int u){ return __uint_as_float(u << 16); }
__device__ __forceinline__ bf16_t f2bf(float f){
    unsigned int u = __float_as_uint(f);
    u += 0x7fffu + ((u >> 16) & 1u);   // RNE
    return (bf16_t)(u >> 16);
}

// ---------------- setup kernels ----------------

__global__ void zero_int(int* __restrict__ p, int n){
    int i = blockIdx.x * 256 + threadIdx.x;
    if (i < n) p[i] = 0;
}

__global__ void count_deg(const int* __restrict__ src, const int* __restrict__ dst,
                          int* __restrict__ dout, int* __restrict__ din, int E){
    int i = blockIdx.x * 256 + threadIdx.x;
    if (i < E){
        atomicAdd(&dout[src[i]], 1);
        atomicAdd(&din[dst[i]], 1);
    }
}

__global__ void norm_k(const int* __restrict__ dout, const int* __restrict__ din,
                       float* __restrict__ nsrc, float* __restrict__ ndst, int n){
    int i = blockIdx.x * 256 + threadIdx.x;
    if (i < n){
        nsrc[i] = rsqrtf(fmaxf((float)dout[i], 1.f));
        ndst[i] = rsqrtf(fmaxf((float)din[i], 1.f));
    }
}

__global__ void scan_block(const int* __restrict__ in, int* __restrict__ out,
                           int* __restrict__ bsums, int n){
    __shared__ int tmp[1024];
    int t = threadIdx.x;
    int i = blockIdx.x * 1024 + t;
    int v = (i < n) ? in[i] : 0;
    tmp[t] = v; __syncthreads();
    for (int off = 1; off < 1024; off <<= 1){
        int x = (t >= off) ? tmp[t - off] : 0;
        __syncthreads();
        tmp[t] += x;
        __syncthreads();
    }
    if (i < n) out[i] = tmp[t] - v;           // exclusive
    if (bsums && t == 1023) bsums[blockIdx.x] = tmp[1023];
}

__global__ void add_offs(int* __restrict__ rp, int* __restrict__ cur,
                         const int* __restrict__ bsums, int n){
    int i = blockIdx.x * 1024 + threadIdx.x;
    if (i < n){
        int v = rp[i] + bsums[blockIdx.x];
        rp[i] = v;
        cur[i] = v;
    }
}

__global__ void fill_csr(const int* __restrict__ src, const int* __restrict__ dst,
                         int* __restrict__ cur, int* __restrict__ csr, int E){
    int i = blockIdx.x * 256 + threadIdx.x;
    if (i < E){
        int pos = atomicAdd(&cur[dst[i]], 1);
        csr[pos] = src[i];
    }
}

// W f32 [K,N] row-major -> WT bf16 [N,K] row-major (fused transpose + cast)
__global__ void transpose_w(const float* __restrict__ W, bf16_t* __restrict__ WT, int K, int N){
    int i = blockIdx.x * 256 + threadIdx.x;
    if (i < K * N){
        int k = i / N, n = i - k * N;
        WT[n * K + k] = f2bf(W[i]);
    }
}

// ---------------- GEMM: C = act(A @ B + bias) * rowscale, C bf16 ----------------
// A [M,512] f32 (A_F32) or bf16; BT bf16 [N,512]; fp32 accumulate via mfma 16x16x32.
// 128x128 tile, 4 waves 2x2, 4x4 frags/wave.

template<bool A_F32>
__global__ __launch_bounds__(256) void gemm_k(
    const void* __restrict__ Aptr, const bf16_t* __restrict__ BT,
    const float* __restrict__ bias, const float* __restrict__ rowscale,
    bf16_t* __restrict__ Cmat, int M, int N, int doRelu)
{
    const int K = DDIM;
    __shared__ __align__(16) bf16_t As[128 * KPAD];
    __shared__ __align__(16) bf16_t Bs[128 * KPAD];
    int tid = threadIdx.x;
    int m0 = blockIdx.x * 128, n0 = blockIdx.y * 128;
    int wave = tid >> 6, lane = tid & 63;
    int wm = (wave >> 1) * 64, wn = (wave & 1) * 64;
    int quad = lane >> 4, r16 = lane & 15;

    f32x4 acc[4][4];
    #pragma unroll
    for (int i = 0; i < 4; i++)
        #pragma unroll
        for (int j = 0; j < 4; j++)
            acc[i][j] = (f32x4){0.f, 0.f, 0.f, 0.f};

    for (int k0 = 0; k0 < K; k0 += 32){
        float4 av[4];       // A_F32 path: 1024 float4 slots
        uint4  a16[2];      // bf16 path: 512 uint4 slots
        uint4  bv[2];
        if (A_F32){
            const float* A = (const float*)Aptr;
            #pragma unroll
            for (int j = 0; j < 4; j++){
                int slot = tid + j * 256;
                int row = slot >> 3, c4 = slot & 7;
                av[j] = (float4){0.f, 0.f, 0.f, 0.f};
                if (m0 + row < M) av[j] = *(const float4*)(A + (size_t)(m0 + row) * K + k0 + c4 * 4);
            }
        } else {
            const bf16_t* A = (const bf16_t*)Aptr;
            #pragma unroll
            for (int j = 0; j < 2; j++){
                int slot = tid + j * 256;
                int row = slot >> 2, c8 = slot & 3;
                a16[j] = (uint4){0, 0, 0, 0};
                if (m0 + row < M) a16[j] = *(const uint4*)(A + (size_t)(m0 + row) * K + k0 + c8 * 8);
            }
        }
        #pragma unroll
        for (int j = 0; j < 2; j++){
            int slot = tid + j * 256;
            int row = slot >> 2, c8 = slot & 3;
            bv[j] = (uint4){0, 0, 0, 0};
            if (n0 + row < N) bv[j] = *(const uint4*)(BT + (size_t)(n0 + row) * K + k0 + c8 * 8);
        }
        __syncthreads();
        if (A_F32){
            #pragma unroll
            for (int j = 0; j < 4; j++){
                int slot = tid + j * 256;
                int row = slot >> 3, c4 = slot & 7;
                ushort4 ap;
                ap.x = f2bf(av[j].x); ap.y = f2bf(av[j].y);
                ap.z = f2bf(av[j].z); ap.w = f2bf(av[j].w);
                *(ushort4*)&As[row * KPAD + c4 * 4] = ap;
            }
        } else {
            #pragma unroll
            for (int j = 0; j < 2; j++){
                int slot = tid + j * 256;
                int row = slot >> 2, c8 = slot & 3;
                *(uint4*)&As[row * KPAD + c8 * 8] = a16[j];
            }
        }
        #pragma unroll
        for (int j = 0; j < 2; j++){
            int slot = tid + j * 256;
            int row = slot >> 2, c8 = slot & 3;
            *(uint4*)&Bs[row * KPAD + c8 * 8] = bv[j];
        }
        __syncthreads();

        bf16x8 af[4], bfr[4];
        #pragma unroll
        for (int mi = 0; mi < 4; mi++)
            af[mi] = *(const bf16x8*)&As[(wm + mi * 16 + r16) * KPAD + quad * 8];
        #pragma unroll
        for (int ni = 0; ni < 4; ni++)
            bfr[ni] = *(const bf16x8*)&Bs[(wn + ni * 16 + r16) * KPAD + quad * 8];
        #pragma unroll
        for (int mi = 0; mi < 4; mi++)
            #pragma unroll
            for (int ni = 0; ni < 4; ni++)
                acc[mi][ni] = __builtin_amdgcn_mfma_f32_16x16x32_bf16(af[mi], bfr[ni], acc[mi][ni], 0, 0, 0);
    }

    // C/D layout: col = lane&15, row = quad*4 + reg  [m89/m91-verified]
    #pragma unroll
    for (int mi = 0; mi < 4; mi++){
        int rbase = m0 + wm + mi * 16 + quad * 4;
        #pragma unroll
        for (int ni = 0; ni < 4; ni++){
            int c = n0 + wn + ni * 16 + r16;
            if (c < N){
                float bvv = bias ? bias[c] : 0.f;
                #pragma unroll
                for (int r = 0; r < 4; r++){
                    int row = rbase + r;
                    if (row < M){
                        float val = acc[mi][ni][r] + bvv;
                        if (doRelu) val = fmaxf(val, 0.f);
                        if (rowscale) val *= rowscale[row];
                        Cmat[(size_t)row * N + c] = f2bf(val);
                    }
                }
            }
        }
    }
}

// ---------------- SpMM (CSR by dst): out[v] = ndst[v]*sum g[u], 512-dim bf16 ----------------
// one wave per node; lane holds 8 bf16 (16B) -> per edge the wave reads one contiguous 1 KB row.
// R1 showed the kernel is memory-system-THROUGHPUT bound (unroll/occupancy-insensitive at
// 3.76 TB/s beyond-L2, FETCH=1.59 GB vs 3.2 GB logical => MALL holds only ~50% of G).
// R2 theory: the 102 MB H2 output stream write-allocates and thrashes G out of the MALL.
// Fix: NON-TEMPORAL stores for the output so MALL retains G (102 MB) + csr (12.8 MB).
// 8-deep unroll kept (MLP matters again once G is cache-served).

__global__ __launch_bounds__(256) void spmm512(
    const bf16_t* __restrict__ g, const int* __restrict__ csr,
    const int* __restrict__ rp, const int* __restrict__ deg,
    const float* __restrict__ ndst, bf16_t* __restrict__ outm, int nn)
{
    int wave = threadIdx.x >> 6, lane = threadIdx.x & 63;
    int v = blockIdx.x * 4 + wave;
    if (v >= nn) return;
    int start = rp[v], cnt = deg[v];
    const int* ep = csr + start;
    int loff = lane << 3;                       // this lane's 8-element (16B) chunk
    float acc[8] = {0,0,0,0,0,0,0,0};

#define SPG(j, idx) \
    int u##j = __builtin_amdgcn_readfirstlane(ep[idx]); \
    uint4 d##j = *(const uint4*)(g + (size_t)u##j * DDIM + loff);
#define SPA(j) \
    acc[0] += bf2f(d##j.x & 0xffffu); acc[1] += bf2f(d##j.x >> 16); \
    acc[2] += bf2f(d##j.y & 0xffffu); acc[3] += bf2f(d##j.y >> 16); \
    acc[4] += bf2f(d##j.z & 0xffffu); acc[5] += bf2f(d##j.z >> 16); \
    acc[6] += bf2f(d##j.w & 0xffffu); acc[7] += bf2f(d##j.w >> 16);

    int e = 0, full8 = cnt & ~7;
    for (; e < full8; e += 8){
        SPG(0, e + 0) SPG(1, e + 1) SPG(2, e + 2) SPG(3, e + 3)
        SPG(4, e + 4) SPG(5, e + 5) SPG(6, e + 6) SPG(7, e + 7)
        SPA(0) SPA(1) SPA(2) SPA(3) SPA(4) SPA(5) SPA(6) SPA(7)
    }
    int rem = cnt - e;                          // 0..7
    if (rem){
        int cl = e + rem - 1;                   // clamp index (valid, already-hot row -> L1 hit)
        SPG(0, e)
        SPG(1, 1 < rem ? e + 1 : cl)
        SPG(2, 2 < rem ? e + 2 : cl)
        SPG(3, 3 < rem ? e + 3 : cl)
        SPG(4, 4 < rem ? e + 4 : cl)
        SPG(5, 5 < rem ? e + 5 : cl)
        SPG(6, 6 < rem ? e + 6 : cl)
        SPA(0)
        if (rem > 1){ SPA(1) }
        if (rem > 2){ SPA(2) }
        if (rem > 3){ SPA(3) }
        if (rem > 4){ SPA(4) }
        if (rem > 5){ SPA(5) }
        if (rem > 6){ SPA(6) }
    }
#undef SPG
#undef SPA

    float s = ndst[v];
    u32x4 o;
    o.x = (unsigned)f2bf(acc[0] * s) | ((unsigned)f2bf(acc[1] * s) << 16);
    o.y = (unsigned)f2bf(acc[2] * s) | ((unsigned)f2bf(acc[3] * s) << 16);
    o.z = (unsigned)f2bf(acc[4] * s) | ((unsigned)f2bf(acc[5] * s) << 16);
    o.w = (unsigned)f2bf(acc[6] * s) | ((unsigned)f2bf(acc[7] * s) << 16);
    // nt store: do NOT write-allocate H2 in L2/MALL -> keep G resident
    __builtin_nontemporal_store(o, (u32x4*)(outm + (size_t)v * DDIM + loff));
}

// 40-dim SpMM for the last layer (GEMM commuted ahead of it): out = ndst*sum + b2, f32 out
// Same 8-deep unroll for memory-level parallelism.

__global__ __launch_bounds__(256) void spmm40(
    const bf16_t* __restrict__ p40, const int* __restrict__ csr,
    const int* __restrict__ rp, const int* __restrict__ deg,
    const float* __restrict__ ndst, const float* __restrict__ b2,
    float* __restrict__ out, int nn)
{
    int wave = threadIdx.x >> 6, lane = threadIdx.x & 63;
    int v = blockIdx.x * 4 + wave;
    if (v >= nn || lane >= NCLS) return;
    int start = rp[v], cnt = deg[v];
    const int* ep = csr + start;
    float acc = 0.f;

#define SQG(j, idx) \
    int w##j = __builtin_amdgcn_readfirstlane(ep[idx]); \
    unsigned short t##j = p40[(size_t)w##j * NCLS + lane];
#define SQA(j) acc += bf2f((unsigned)t##j);

    int e = 0, full8 = cnt & ~7;
    for (; e < full8; e += 8){
        SQG(0, e + 0) SQG(1, e + 1) SQG(2, e + 2) SQG(3, e + 3)
        SQG(4, e + 4) SQG(5, e + 5) SQG(6, e + 6) SQG(7, e + 7)
        SQA(0) SQA(1) SQA(2) SQA(3) SQA(4) SQA(5) SQA(6) SQA(7)
    }
    int rem = cnt - e;
    if (rem){
        int cl = e + rem - 1;
        SQG(0, e)
        SQG(1, 1 < rem ? e + 1 : cl)
        SQG(2, 2 < rem ? e + 2 : cl)
        SQG(3, 3 < rem ? e + 3 : cl)
        SQG(4, 4 < rem ? e + 4 : cl)
        SQG(5, 5 < rem ? e + 5 : cl)
        SQG(6, 6 < rem ? e + 6 : cl)
        SQA(0)
        if (rem > 1){ SQA(1) }
        if (rem > 2){ SQA(2) }
        if (rem > 3){ SQA(3) }
        if (rem > 4){ SQA(4) }
        if (rem > 5){ SQA(5) }
        if (rem > 6){ SQA(6) }
    }
#undef SQG
#undef SQA

    out[(size_t)v * NCLS + lane] = acc * ndst[v] + b2[lane];
}

// ---------------- launch ----------------
// bf16 intermediates: G (d_ws, 102.4 MB) is the spmm gather source. MALL budget:
// G (102 MB) + csr (12.8 MB) + H2 read-side (102 MB during GEMM) = ~217 MB < 256 MB,
// PROVIDED the spmm H2 write stream does not allocate (nt stores). H2/P live in
// d_in[0] (restored pre-launch => legal scratch after its last read). ws use ~119 MB.

extern "C" void kernel_launch(void* const* d_in, const int* in_sizes, int n_in,
                              void* d_out, int out_size, void* d_ws, size_t ws_size,
                              hipStream_t stream)
{
    const float* feat = (const float*)d_in[0];
    const int*   src  = (const int*)d_in[1];
    const int*   dst  = (const int*)d_in[2];
    const float* Wlin = (const float*)d_in[3];
    const float* blin = (const float*)d_in[4];
    const float* W0   = (const float*)d_in[5];
    const float* b0   = (const float*)d_in[6];
    const float* W1   = (const float*)d_in[7];
    const float* b1   = (const float*)d_in[8];
    const float* W2   = (const float*)d_in[9];
    const float* b2   = (const float*)d_in[10];

    const int NN = NNODES;
    const int E  = in_sizes[1];

    char* wsp = (char*)d_ws;
    auto alloc = [&](size_t bytes) -> char* {
        char* r = wsp;
        wsp += (bytes + 255) & ~(size_t)255;
        return r;
    };
    int*    deg_out = (int*)alloc((size_t)NN * 4);
    int*    deg_in  = (int*)alloc((size_t)NN * 4);
    float*  nsrc    = (float*)alloc((size_t)NN * 4);
    float*  ndst    = (float*)alloc((size_t)NN * 4);
    int*    row_ptr = (int*)alloc((size_t)NN * 4);
    int*    cursor  = (int*)alloc((size_t)NN * 4);
    int*    bsums   = (int*)alloc(1024);
    bf16_t* WTlin   = (bf16_t*)alloc((size_t)512 * 512 * 2);
    bf16_t* WT0     = (bf16_t*)alloc((size_t)512 * 512 * 2);
    bf16_t* WT1     = (bf16_t*)alloc((size_t)512 * 512 * 2);
    bf16_t* W2T     = (bf16_t*)alloc((size_t)NCLS * 512 * 2);
    int*    csr     = (int*)alloc((size_t)E * 4);
    bf16_t* G       = (bf16_t*)alloc((size_t)NN * DDIM * 2);   // 102.4 MB, MALL-resident target

    bf16_t* H2 = (bf16_t*)d_in[0];   // feat dead after first GEMM
    bf16_t* P  = (bf16_t*)d_in[0];   // 8 MB logits scratch once H2 dead

    int eb   = (E + 255) / 256;
    int nb   = (NN + 255) / 256;
    int sb   = (NN + 1023) / 1024;
    dim3 g512((NN + 127) / 128, 4);
    dim3 g40 ((NN + 127) / 128, 1);
    int  sp  = (NN + 3) / 4;

    zero_int<<<nb, 256, 0, stream>>>(deg_out, NN);
    zero_int<<<nb, 256, 0, stream>>>(deg_in, NN);
    count_deg<<<eb, 256, 0, stream>>>(src, dst, deg_out, deg_in, E);
    norm_k<<<nb, 256, 0, stream>>>(deg_out, deg_in, nsrc, ndst, NN);

    scan_block<<<sb, 1024, 0, stream>>>(deg_in, row_ptr, bsums, NN);
    scan_block<<<1, 1024, 0, stream>>>(bsums, bsums, nullptr, sb);
    add_offs<<<sb, 1024, 0, stream>>>(row_ptr, cursor, bsums, NN);
    fill_csr<<<eb, 256, 0, stream>>>(src, dst, cursor, csr, E);

    transpose_w<<<(512 * 512 + 255) / 256, 256, 0, stream>>>(Wlin, WTlin, 512, 512);
    transpose_w<<<(512 * 512 + 255) / 256, 256, 0, stream>>>(W0, WT0, 512, 512);
    transpose_w<<<(512 * 512 + 255) / 256, 256, 0, stream>>>(W1, WT1, 512, 512);
    transpose_w<<<(512 * NCLS + 255) / 256, 256, 0, stream>>>(W2, W2T, 512, NCLS);

    // g0 = (X @ Wlin + blin) * norm_src          (feat dead after this)
    gemm_k<true ><<<g512, 256, 0, stream>>>(feat, WTlin, blin, nsrc, G, NN, 512, 0);
    // m0' = norm_dst * segsum(g0)
    spmm512<<<sp, 256, 0, stream>>>(G, csr, row_ptr, deg_in, ndst, H2, NN);
    // g1 = relu(m0' @ W0 + b0) * norm_src
    gemm_k<false><<<g512, 256, 0, stream>>>(H2, WT0, b0, nsrc, G, NN, 512, 1);
    // m1' = norm_dst * segsum(g1)
    spmm512<<<sp, 256, 0, stream>>>(G, csr, row_ptr, deg_in, ndst, H2, NN);
    // g2 = relu(m1' @ W1 + b1) * norm_src
    gemm_k<false><<<g512, 256, 0, stream>>>(H2, WT1, b1, nsrc, G, NN, 512, 1);
    // p = g2 @ W2   (GEMM commuted ahead of the final SpMM; H2 dead now)
    gemm_k<false><<<g40, 256, 0, stream>>>(G, W2T, nullptr, nullptr, P, NN, NCLS, 0);
    // out = norm_dst * segsum(p) + b2
    spmm40<<<sp, 256, 0, stream>>>(P, csr, row_ptr, deg_in, ndst, b2, (float*)d_out, NN);
}

// Round 3
// 2305.064 us; speedup vs baseline: 1.0272x; 1.0272x over previous
//
#include <hip/hip_runtime.h>

#define NNODES 100000
#define DDIM   512
#define NCLS   40
#define KPAD   56   // LDS bf16 row stride: 112B = 16B-aligned rows, 2-way bank aliasing (free, m136)

typedef unsigned short bf16_t;
typedef short bf16x8 __attribute__((ext_vector_type(8)));   // gfx950 bf16 MFMA frag (guide §3)
typedef float f32x4  __attribute__((ext_vector_type(4)));

__device__ __forceinline__ float bf2f(unsigned int u){ return __uint_as_float(u << 16); }
__device__ __forceinline__ bf16_t f2bf(float f){
    unsigned int u = __float_as_uint(f);
    u += 0x7fffu + ((u >> 16) & 1u);   // RNE
    return (bf16_t)(u >> 16);
}

// ---------------- setup kernels ----------------

__global__ void zero_int(int* __restrict__ p, int n){
    int i = blockIdx.x * 256 + threadIdx.x;
    if (i < n) p[i] = 0;
}

__global__ void count_deg(const int* __restrict__ src, const int* __restrict__ dst,
                          int* __restrict__ dout, int* __restrict__ din, int E){
    int i = blockIdx.x * 256 + threadIdx.x;
    if (i < E){
        atomicAdd(&dout[src[i]], 1);
        atomicAdd(&din[dst[i]], 1);
    }
}

__global__ void norm_k(const int* __restrict__ dout, const int* __restrict__ din,
                       float* __restrict__ nsrc, float* __restrict__ ndst, int n){
    int i = blockIdx.x * 256 + threadIdx.x;
    if (i < n){
        nsrc[i] = rsqrtf(fmaxf((float)dout[i], 1.f));
        ndst[i] = rsqrtf(fmaxf((float)din[i], 1.f));
    }
}

__global__ void scan_block(const int* __restrict__ in, int* __restrict__ out,
                           int* __restrict__ bsums, int n){
    __shared__ int tmp[1024];
    int t = threadIdx.x;
    int i = blockIdx.x * 1024 + t;
    int v = (i < n) ? in[i] : 0;
    tmp[t] = v; __syncthreads();
    for (int off = 1; off < 1024; off <<= 1){
        int x = (t >= off) ? tmp[t - off] : 0;
        __syncthreads();
        tmp[t] += x;
        __syncthreads();
    }
    if (i < n) out[i] = tmp[t] - v;           // exclusive
    if (bsums && t == 1023) bsums[blockIdx.x] = tmp[1023];
}

__global__ void add_offs(int* __restrict__ rp, int* __restrict__ cur,
                         const int* __restrict__ bsums, int n){
    int i = blockIdx.x * 1024 + threadIdx.x;
    if (i < n){
        int v = rp[i] + bsums[blockIdx.x];
        rp[i] = v;
        cur[i] = v;
    }
}

__global__ void fill_csr(const int* __restrict__ src, const int* __restrict__ dst,
                         int* __restrict__ cur, int* __restrict__ csr, int E){
    int i = blockIdx.x * 256 + threadIdx.x;
    if (i < E){
        int pos = atomicAdd(&cur[dst[i]], 1);
        csr[pos] = src[i];
    }
}

// W f32 [K,N] row-major -> WT bf16 [N,K] row-major (fused transpose + cast)
__global__ void transpose_w(const float* __restrict__ W, bf16_t* __restrict__ WT, int K, int N){
    int i = blockIdx.x * 256 + threadIdx.x;
    if (i < K * N){
        int k = i / N, n = i - k * N;
        WT[n * K + k] = f2bf(W[i]);
    }
}

// ---------------- GEMM: C = act(A @ B + bias) * rowscale, C bf16 ----------------
// A [M,512] f32 (A_F32) or bf16; BT bf16 [N,512]; fp32 accumulate via mfma 16x16x32.
// 128x128 tile, 4 waves 2x2, 4x4 frags/wave.

template<bool A_F32>
__global__ __launch_bounds__(256) void gemm_k(
    const void* __restrict__ Aptr, const bf16_t* __restrict__ BT,
    const float* __restrict__ bias, const float* __restrict__ rowscale,
    bf16_t* __restrict__ Cmat, int M, int N, int doRelu)
{
    const int K = DDIM;
    __shared__ __align__(16) bf16_t As[128 * KPAD];
    __shared__ __align__(16) bf16_t Bs[128 * KPAD];
    int tid = threadIdx.x;
    int m0 = blockIdx.x * 128, n0 = blockIdx.y * 128;
    int wave = tid >> 6, lane = tid & 63;
    int wm = (wave >> 1) * 64, wn = (wave & 1) * 64;
    int quad = lane >> 4, r16 = lane & 15;

    f32x4 acc[4][4];
    #pragma unroll
    for (int i = 0; i < 4; i++)
        #pragma unroll
        for (int j = 0; j < 4; j++)
            acc[i][j] = (f32x4){0.f, 0.f, 0.f, 0.f};

    for (int k0 = 0; k0 < K; k0 += 32){
        float4 av[4];       // A_F32 path: 1024 float4 slots
        uint4  a16[2];      // bf16 path: 512 uint4 slots
        uint4  bv[2];
        if (A_F32){
            const float* A = (const float*)Aptr;
            #pragma unroll
            for (int j = 0; j < 4; j++){
                int slot = tid + j * 256;
                int row = slot >> 3, c4 = slot & 7;
                av[j] = (float4){0.f, 0.f, 0.f, 0.f};
                if (m0 + row < M) av[j] = *(const float4*)(A + (size_t)(m0 + row) * K + k0 + c4 * 4);
            }
        } else {
            const bf16_t* A = (const bf16_t*)Aptr;
            #pragma unroll
            for (int j = 0; j < 2; j++){
                int slot = tid + j * 256;
                int row = slot >> 2, c8 = slot & 3;
                a16[j] = (uint4){0, 0, 0, 0};
                if (m0 + row < M) a16[j] = *(const uint4*)(A + (size_t)(m0 + row) * K + k0 + c8 * 8);
            }
        }
        #pragma unroll
        for (int j = 0; j < 2; j++){
            int slot = tid + j * 256;
            int row = slot >> 2, c8 = slot & 3;
            bv[j] = (uint4){0, 0, 0, 0};
            if (n0 + row < N) bv[j] = *(const uint4*)(BT + (size_t)(n0 + row) * K + k0 + c8 * 8);
        }
        __syncthreads();
        if (A_F32){
            #pragma unroll
            for (int j = 0; j < 4; j++){
                int slot = tid + j * 256;
                int row = slot >> 3, c4 = slot & 7;
                ushort4 ap;
                ap.x = f2bf(av[j].x); ap.y = f2bf(av[j].y);
                ap.z = f2bf(av[j].z); ap.w = f2bf(av[j].w);
                *(ushort4*)&As[row * KPAD + c4 * 4] = ap;
            }
        } else {
            #pragma unroll
            for (int j = 0; j < 2; j++){
                int slot = tid + j * 256;
                int row = slot >> 2, c8 = slot & 3;
                *(uint4*)&As[row * KPAD + c8 * 8] = a16[j];
            }
        }
        #pragma unroll
        for (int j = 0; j < 2; j++){
            int slot = tid + j * 256;
            int row = slot >> 2, c8 = slot & 3;
            *(uint4*)&Bs[row * KPAD + c8 * 8] = bv[j];
        }
        __syncthreads();

        bf16x8 af[4], bfr[4];
        #pragma unroll
        for (int mi = 0; mi < 4; mi++)
            af[mi] = *(const bf16x8*)&As[(wm + mi * 16 + r16) * KPAD + quad * 8];
        #pragma unroll
        for (int ni = 0; ni < 4; ni++)
            bfr[ni] = *(const bf16x8*)&Bs[(wn + ni * 16 + r16) * KPAD + quad * 8];
        #pragma unroll
        for (int mi = 0; mi < 4; mi++)
            #pragma unroll
            for (int ni = 0; ni < 4; ni++)
                acc[mi][ni] = __builtin_amdgcn_mfma_f32_16x16x32_bf16(af[mi], bfr[ni], acc[mi][ni], 0, 0, 0);
    }

    // C/D layout: col = lane&15, row = quad*4 + reg  [m89/m91-verified]
    #pragma unroll
    for (int mi = 0; mi < 4; mi++){
        int rbase = m0 + wm + mi * 16 + quad * 4;
        #pragma unroll
        for (int ni = 0; ni < 4; ni++){
            int c = n0 + wn + ni * 16 + r16;
            if (c < N){
                float bvv = bias ? bias[c] : 0.f;
                #pragma unroll
                for (int r = 0; r < 4; r++){
                    int row = rbase + r;
                    if (row < M){
                        float val = acc[mi][ni][r] + bvv;
                        if (doRelu) val = fmaxf(val, 0.f);
                        if (rowscale) val *= rowscale[row];
                        Cmat[(size_t)row * N + c] = f2bf(val);
                    }
                }
            }
        }
    }
}

// ---------------- SpMM (CSR by dst), D-SPLIT: out[v,d0:d0+256] = ndst[v]*sum g[u,d0:d0+256] --
// R1: throughput-bound, not latency (8x MLP = null). R2: nt-store = null.
// R3 theory: DRAM random-read (~3.5 TB/s) binds because the 102 MB G + 102 MB H2 stream
// + csr churn the 256 MB MALL (FETCH 1.59 GB = 50% of logical 3.2 GB). Fix: two
// sequential half-D passes; per-pass hot set = 51 (G-half) + 51 (H2-half) + 13 (csr)
// = 115 MB << 256 MB -> G-half stays MALL-resident, DRAM fetch ~compulsory.
// Per-output-element edge order unchanged -> bit-identical numerics.
// 8-deep unroll kept; 8 B/lane (uint2) gathers: 512 B contiguous per edge instruction.

__global__ __launch_bounds__(256) void spmm512h(
    const bf16_t* __restrict__ g, const int* __restrict__ csr,
    const int* __restrict__ rp, const int* __restrict__ deg,
    const float* __restrict__ ndst, bf16_t* __restrict__ outm, int nn, int d0)
{
    int wave = threadIdx.x >> 6, lane = threadIdx.x & 63;
    int v = blockIdx.x * 4 + wave;
    if (v >= nn) return;
    int start = rp[v], cnt = deg[v];
    const int* ep = csr + start;
    int loff = d0 + (lane << 2);                // this lane's 4-element (8B) chunk of the half
    const bf16_t* base = g + loff;
    float acc[4] = {0,0,0,0};

#define SPG(j, idx) \
    int u##j = __builtin_amdgcn_readfirstlane(ep[idx]); \
    uint2 d##j = *(const uint2*)(base + (size_t)u##j * DDIM);
#define SPA(j) \
    acc[0] += bf2f(d##j.x & 0xffffu); acc[1] += bf2f(d##j.x >> 16); \
    acc[2] += bf2f(d##j.y & 0xffffu); acc[3] += bf2f(d##j.y >> 16);

    int e = 0, full8 = cnt & ~7;
    for (; e < full8; e += 8){
        SPG(0, e + 0) SPG(1, e + 1) SPG(2, e + 2) SPG(3, e + 3)
        SPG(4, e + 4) SPG(5, e + 5) SPG(6, e + 6) SPG(7, e + 7)
        SPA(0) SPA(1) SPA(2) SPA(3) SPA(4) SPA(5) SPA(6) SPA(7)
    }
    int rem = cnt - e;                          // 0..7
    if (rem){
        int cl = e + rem - 1;                   // clamp index (valid, already-hot row)
        SPG(0, e)
        SPG(1, 1 < rem ? e + 1 : cl)
        SPG(2, 2 < rem ? e + 2 : cl)
        SPG(3, 3 < rem ? e + 3 : cl)
        SPG(4, 4 < rem ? e + 4 : cl)
        SPG(5, 5 < rem ? e + 5 : cl)
        SPG(6, 6 < rem ? e + 6 : cl)
        SPA(0)
        if (rem > 1){ SPA(1) }
        if (rem > 2){ SPA(2) }
        if (rem > 3){ SPA(3) }
        if (rem > 4){ SPA(4) }
        if (rem > 5){ SPA(5) }
        if (rem > 6){ SPA(6) }
    }
#undef SPG
#undef SPA

    float s = ndst[v];
    uint2 o;
    o.x = (unsigned)f2bf(acc[0] * s) | ((unsigned)f2bf(acc[1] * s) << 16);
    o.y = (unsigned)f2bf(acc[2] * s) | ((unsigned)f2bf(acc[3] * s) << 16);
    *(uint2*)(outm + (size_t)v * DDIM + loff) = o;
}

// 40-dim SpMM for the last layer (GEMM commuted ahead of it): out = ndst*sum + b2, f32 out
// Working set: p40 = 8 MB -> already cache-resident; 8-deep unroll for MLP.

__global__ __launch_bounds__(256) void spmm40(
    const bf16_t* __restrict__ p40, const int* __restrict__ csr,
    const int* __restrict__ rp, const int* __restrict__ deg,
    const float* __restrict__ ndst, const float* __restrict__ b2,
    float* __restrict__ out, int nn)
{
    int wave = threadIdx.x >> 6, lane = threadIdx.x & 63;
    int v = blockIdx.x * 4 + wave;
    if (v >= nn || lane >= NCLS) return;
    int start = rp[v], cnt = deg[v];
    const int* ep = csr + start;
    float acc = 0.f;

#define SQG(j, idx) \
    int w##j = __builtin_amdgcn_readfirstlane(ep[idx]); \
    unsigned short t##j = p40[(size_t)w##j * NCLS + lane];
#define SQA(j) acc += bf2f((unsigned)t##j);

    int e = 0, full8 = cnt & ~7;
    for (; e < full8; e += 8){
        SQG(0, e + 0) SQG(1, e + 1) SQG(2, e + 2) SQG(3, e + 3)
        SQG(4, e + 4) SQG(5, e + 5) SQG(6, e + 6) SQG(7, e + 7)
        SQA(0) SQA(1) SQA(2) SQA(3) SQA(4) SQA(5) SQA(6) SQA(7)
    }
    int rem = cnt - e;
    if (rem){
        int cl = e + rem - 1;
        SQG(0, e)
        SQG(1, 1 < rem ? e + 1 : cl)
        SQG(2, 2 < rem ? e + 2 : cl)
        SQG(3, 3 < rem ? e + 3 : cl)
        SQG(4, 4 < rem ? e + 4 : cl)
        SQG(5, 5 < rem ? e + 5 : cl)
        SQG(6, 6 < rem ? e + 6 : cl)
        SQA(0)
        if (rem > 1){ SQA(1) }
        if (rem > 2){ SQA(2) }
        if (rem > 3){ SQA(3) }
        if (rem > 4){ SQA(4) }
        if (rem > 5){ SQA(5) }
        if (rem > 6){ SQA(6) }
    }
#undef SQG
#undef SQA

    out[(size_t)v * NCLS + lane] = acc * ndst[v] + b2[lane];
}

// ---------------- launch ----------------
// bf16 intermediates: G (d_ws, 102.4 MB) is the spmm gather source. SpMM runs as two
// sequential half-D passes so the per-pass hot set (~115 MB) fits the 256 MB MALL.
// H2/P live in d_in[0] (restored pre-launch => legal scratch after its last read).

extern "C" void kernel_launch(void* const* d_in, const int* in_sizes, int n_in,
                              void* d_out, int out_size, void* d_ws, size_t ws_size,
                              hipStream_t stream)
{
    const float* feat = (const float*)d_in[0];
    const int*   src  = (const int*)d_in[1];
    const int*   dst  = (const int*)d_in[2];
    const float* Wlin = (const float*)d_in[3];
    const float* blin = (const float*)d_in[4];
    const float* W0   = (const float*)d_in[5];
    const float* b0   = (const float*)d_in[6];
    const float* W1   = (const float*)d_in[7];
    const float* b1   = (const float*)d_in[8];
    const float* W2   = (const float*)d_in[9];
    const float* b2   = (const float*)d_in[10];

    const int NN = NNODES;
    const int E  = in_sizes[1];

    char* wsp = (char*)d_ws;
    auto alloc = [&](size_t bytes) -> char* {
        char* r = wsp;
        wsp += (bytes + 255) & ~(size_t)255;
        return r;
    };
    int*    deg_out = (int*)alloc((size_t)NN * 4);
    int*    deg_in  = (int*)alloc((size_t)NN * 4);
    float*  nsrc    = (float*)alloc((size_t)NN * 4);
    float*  ndst    = (float*)alloc((size_t)NN * 4);
    int*    row_ptr = (int*)alloc((size_t)NN * 4);
    int*    cursor  = (int*)alloc((size_t)NN * 4);
    int*    bsums   = (int*)alloc(1024);
    bf16_t* WTlin   = (bf16_t*)alloc((size_t)512 * 512 * 2);
    bf16_t* WT0     = (bf16_t*)alloc((size_t)512 * 512 * 2);
    bf16_t* WT1     = (bf16_t*)alloc((size_t)512 * 512 * 2);
    bf16_t* W2T     = (bf16_t*)alloc((size_t)NCLS * 512 * 2);
    int*    csr     = (int*)alloc((size_t)E * 4);
    bf16_t* G       = (bf16_t*)alloc((size_t)NN * DDIM * 2);   // 102.4 MB

    bf16_t* H2 = (bf16_t*)d_in[0];   // feat dead after first GEMM
    bf16_t* P  = (bf16_t*)d_in[0];   // 8 MB logits scratch once H2 dead

    int eb   = (E + 255) / 256;
    int nb   = (NN + 255) / 256;
    int sb   = (NN + 1023) / 1024;
    dim3 g512((NN + 127) / 128, 4);
    dim3 g40 ((NN + 127) / 128, 1);
    int  sp  = (NN + 3) / 4;

    zero_int<<<nb, 256, 0, stream>>>(deg_out, NN);
    zero_int<<<nb, 256, 0, stream>>>(deg_in, NN);
    count_deg<<<eb, 256, 0, stream>>>(src, dst, deg_out, deg_in, E);
    norm_k<<<nb, 256, 0, stream>>>(deg_out, deg_in, nsrc, ndst, NN);

    scan_block<<<sb, 1024, 0, stream>>>(deg_in, row_ptr, bsums, NN);
    scan_block<<<1, 1024, 0, stream>>>(bsums, bsums, nullptr, sb);
    add_offs<<<sb, 1024, 0, stream>>>(row_ptr, cursor, bsums, NN);
    fill_csr<<<eb, 256, 0, stream>>>(src, dst, cursor, csr, E);

    transpose_w<<<(512 * 512 + 255) / 256, 256, 0, stream>>>(Wlin, WTlin, 512, 512);
    transpose_w<<<(512 * 512 + 255) / 256, 256, 0, stream>>>(W0, WT0, 512, 512);
    transpose_w<<<(512 * 512 + 255) / 256, 256, 0, stream>>>(W1, WT1, 512, 512);
    transpose_w<<<(512 * NCLS + 255) / 256, 256, 0, stream>>>(W2, W2T, 512, NCLS);

    // g0 = (X @ Wlin + blin) * norm_src          (feat dead after this)
    gemm_k<true ><<<g512, 256, 0, stream>>>(feat, WTlin, blin, nsrc, G, NN, 512, 0);
    // m0' = norm_dst * segsum(g0)  — two half-D passes (MALL-resident hot set)
    spmm512h<<<sp, 256, 0, stream>>>(G, csr, row_ptr, deg_in, ndst, H2, NN, 0);
    spmm512h<<<sp, 256, 0, stream>>>(G, csr, row_ptr, deg_in, ndst, H2, NN, 256);
    // g1 = relu(m0' @ W0 + b0) * norm_src
    gemm_k<false><<<g512, 256, 0, stream>>>(H2, WT0, b0, nsrc, G, NN, 512, 1);
    // m1' = norm_dst * segsum(g1)
    spmm512h<<<sp, 256, 0, stream>>>(G, csr, row_ptr, deg_in, ndst, H2, NN, 0);
    spmm512h<<<sp, 256, 0, stream>>>(G, csr, row_ptr, deg_in, ndst, H2, NN, 256);
    // g2 = relu(m1' @ W1 + b1) * norm_src
    gemm_k<false><<<g512, 256, 0, stream>>>(H2, WT1, b1, nsrc, G, NN, 512, 1);
    // p = g2 @ W2   (GEMM commuted ahead of the final SpMM; H2 dead now)
    gemm_k<false><<<g40, 256, 0, stream>>>(G, W2T, nullptr, nullptr, P, NN, NCLS, 0);
    // out = norm_dst * segsum(p) + b2
    spmm40<<<sp, 256, 0, stream>>>(P, csr, row_ptr, deg_in, ndst, b2, (float*)d_out, NN);
}

// Round 4
// 2219.877 us; speedup vs baseline: 1.0666x; 1.0384x over previous
//
#include <hip/hip_runtime.h>

#define NNODES 100000
#define DDIM   512
#define NCLS   40
#define KPAD   56   // LDS bf16 row stride: 112B = 16B-aligned rows, 2-way bank aliasing (free, m136)

typedef unsigned short bf16_t;
typedef short bf16x8 __attribute__((ext_vector_type(8)));   // gfx950 bf16 MFMA frag (guide §3)
typedef float f32x4  __attribute__((ext_vector_type(4)));

__device__ __forceinline__ float bf2f(unsigned int u){ return __uint_as_float(u << 16); }
__device__ __forceinline__ bf16_t f2bf(float f){
    unsigned int u = __float_as_uint(f);
    u += 0x7fffu + ((u >> 16) & 1u);   // RNE
    return (bf16_t)(u >> 16);
}

// ---------------- setup kernels ----------------

__global__ void zero_int(int* __restrict__ p, int n){
    int i = blockIdx.x * 256 + threadIdx.x;
    if (i < n) p[i] = 0;
}

__global__ void count_deg(const int* __restrict__ src, const int* __restrict__ dst,
                          int* __restrict__ dout, int* __restrict__ din, int E){
    int i = blockIdx.x * 256 + threadIdx.x;
    if (i < E){
        atomicAdd(&dout[src[i]], 1);
        atomicAdd(&din[dst[i]], 1);
    }
}

__global__ void norm_k(const int* __restrict__ dout, const int* __restrict__ din,
                       float* __restrict__ nsrc, float* __restrict__ ndst, int n){
    int i = blockIdx.x * 256 + threadIdx.x;
    if (i < n){
        nsrc[i] = rsqrtf(fmaxf((float)dout[i], 1.f));
        ndst[i] = rsqrtf(fmaxf((float)din[i], 1.f));
    }
}

__global__ void scan_block(const int* __restrict__ in, int* __restrict__ out,
                           int* __restrict__ bsums, int n){
    __shared__ int tmp[1024];
    int t = threadIdx.x;
    int i = blockIdx.x * 1024 + t;
    int v = (i < n) ? in[i] : 0;
    tmp[t] = v; __syncthreads();
    for (int off = 1; off < 1024; off <<= 1){
        int x = (t >= off) ? tmp[t - off] : 0;
        __syncthreads();
        tmp[t] += x;
        __syncthreads();
    }
    if (i < n) out[i] = tmp[t] - v;           // exclusive
    if (bsums && t == 1023) bsums[blockIdx.x] = tmp[1023];
}

__global__ void add_offs(int* __restrict__ rp, int* __restrict__ cur,
                         const int* __restrict__ bsums, int n){
    int i = blockIdx.x * 1024 + threadIdx.x;
    if (i < n){
        int v = rp[i] + bsums[blockIdx.x];
        rp[i] = v;
        cur[i] = v;
    }
}

// R4: dst-range multi-pass CSR fill. Single-pass scatter had 15x write amplification
// (WRITE_SIZE 194 MB vs 12.8 MB logical, 287 us): random 4B stores into 12.8 MB evict
// partially-dirty lines from 8 non-coherent L2s. Pass p handles dst in [lo,hi) only ->
// csr write window ~3.2 MB + cursor window 100 KB stay L2-resident, lines fill all 16
// slots before flush. All edges of one dst land in exactly one pass (same csr content).
__global__ void fill_csr_pass(const int* __restrict__ src, const int* __restrict__ dst,
                              int* __restrict__ cur, int* __restrict__ csr, int E,
                              int lo, int hi){
    int i = blockIdx.x * 256 + threadIdx.x;
    if (i < E){
        int d = dst[i];
        if (d >= lo && d < hi){
            int pos = atomicAdd(&cur[d], 1);
            csr[pos] = src[i];
        }
    }
}

// W f32 [K,N] row-major -> WT bf16 [N,K] row-major (fused transpose + cast)
__global__ void transpose_w(const float* __restrict__ W, bf16_t* __restrict__ WT, int K, int N){
    int i = blockIdx.x * 256 + threadIdx.x;
    if (i < K * N){
        int k = i / N, n = i - k * N;
        WT[n * K + k] = f2bf(W[i]);
    }
}

// ---------------- GEMM: C = act(A @ B + bias) * rowscale, C bf16 ----------------
// A [M,512] f32 (A_F32) or bf16; BT bf16 [N,512]; fp32 accumulate via mfma 16x16x32.
// 128x128 tile, 4 waves 2x2, 4x4 frags/wave.

template<bool A_F32>
__global__ __launch_bounds__(256) void gemm_k(
    const void* __restrict__ Aptr, const bf16_t* __restrict__ BT,
    const float* __restrict__ bias, const float* __restrict__ rowscale,
    bf16_t* __restrict__ Cmat, int M, int N, int doRelu)
{
    const int K = DDIM;
    __shared__ __align__(16) bf16_t As[128 * KPAD];
    __shared__ __align__(16) bf16_t Bs[128 * KPAD];
    int tid = threadIdx.x;
    int m0 = blockIdx.x * 128, n0 = blockIdx.y * 128;
    int wave = tid >> 6, lane = tid & 63;
    int wm = (wave >> 1) * 64, wn = (wave & 1) * 64;
    int quad = lane >> 4, r16 = lane & 15;

    f32x4 acc[4][4];
    #pragma unroll
    for (int i = 0; i < 4; i++)
        #pragma unroll
        for (int j = 0; j < 4; j++)
            acc[i][j] = (f32x4){0.f, 0.f, 0.f, 0.f};

    for (int k0 = 0; k0 < K; k0 += 32){
        float4 av[4];       // A_F32 path: 1024 float4 slots
        uint4  a16[2];      // bf16 path: 512 uint4 slots
        uint4  bv[2];
        if (A_F32){
            const float* A = (const float*)Aptr;
            #pragma unroll
            for (int j = 0; j < 4; j++){
                int slot = tid + j * 256;
                int row = slot >> 3, c4 = slot & 7;
                av[j] = (float4){0.f, 0.f, 0.f, 0.f};
                if (m0 + row < M) av[j] = *(const float4*)(A + (size_t)(m0 + row) * K + k0 + c4 * 4);
            }
        } else {
            const bf16_t* A = (const bf16_t*)Aptr;
            #pragma unroll
            for (int j = 0; j < 2; j++){
                int slot = tid + j * 256;
                int row = slot >> 2, c8 = slot & 3;
                a16[j] = (uint4){0, 0, 0, 0};
                if (m0 + row < M) a16[j] = *(const uint4*)(A + (size_t)(m0 + row) * K + k0 + c8 * 8);
            }
        }
        #pragma unroll
        for (int j = 0; j < 2; j++){
            int slot = tid + j * 256;
            int row = slot >> 2, c8 = slot & 3;
            bv[j] = (uint4){0, 0, 0, 0};
            if (n0 + row < N) bv[j] = *(const uint4*)(BT + (size_t)(n0 + row) * K + k0 + c8 * 8);
        }
        __syncthreads();
        if (A_F32){
            #pragma unroll
            for (int j = 0; j < 4; j++){
                int slot = tid + j * 256;
                int row = slot >> 3, c4 = slot & 7;
                ushort4 ap;
                ap.x = f2bf(av[j].x); ap.y = f2bf(av[j].y);
                ap.z = f2bf(av[j].z); ap.w = f2bf(av[j].w);
                *(ushort4*)&As[row * KPAD + c4 * 4] = ap;
            }
        } else {
            #pragma unroll
            for (int j = 0; j < 2; j++){
                int slot = tid + j * 256;
                int row = slot >> 2, c8 = slot & 3;
                *(uint4*)&As[row * KPAD + c8 * 8] = a16[j];
            }
        }
        #pragma unroll
        for (int j = 0; j < 2; j++){
            int slot = tid + j * 256;
            int row = slot >> 2, c8 = slot & 3;
            *(uint4*)&Bs[row * KPAD + c8 * 8] = bv[j];
        }
        __syncthreads();

        bf16x8 af[4], bfr[4];
        #pragma unroll
        for (int mi = 0; mi < 4; mi++)
            af[mi] = *(const bf16x8*)&As[(wm + mi * 16 + r16) * KPAD + quad * 8];
        #pragma unroll
        for (int ni = 0; ni < 4; ni++)
            bfr[ni] = *(const bf16x8*)&Bs[(wn + ni * 16 + r16) * KPAD + quad * 8];
        #pragma unroll
        for (int mi = 0; mi < 4; mi++)
            #pragma unroll
            for (int ni = 0; ni < 4; ni++)
                acc[mi][ni] = __builtin_amdgcn_mfma_f32_16x16x32_bf16(af[mi], bfr[ni], acc[mi][ni], 0, 0, 0);
    }

    // C/D layout: col = lane&15, row = quad*4 + reg  [m89/m91-verified]
    #pragma unroll
    for (int mi = 0; mi < 4; mi++){
        int rbase = m0 + wm + mi * 16 + quad * 4;
        #pragma unroll
        for (int ni = 0; ni < 4; ni++){
            int c = n0 + wn + ni * 16 + r16;
            if (c < N){
                float bvv = bias ? bias[c] : 0.f;
                #pragma unroll
                for (int r = 0; r < 4; r++){
                    int row = rbase + r;
                    if (row < M){
                        float val = acc[mi][ni][r] + bvv;
                        if (doRelu) val = fmaxf(val, 0.f);
                        if (rowscale) val *= rowscale[row];
                        Cmat[(size_t)row * N + c] = f2bf(val);
                    }
                }
            }
        }
    }
}

// ---------------- SpMM (CSR by dst), D-SPLIT: out[v,d0:d0+256] = ndst[v]*sum g[u,d0:d0+256] --
// R1: throughput-bound, not latency (8x MLP = null). R2: nt-store = null. R3: D-split
// modest (450->418/layer); effective rate pinned at ~7.8 TB/s through the L2-miss/fabric
// path regardless of MALL residency -> structural ceiling for the random 512B gather.

__global__ __launch_bounds__(256) void spmm512h(
    const bf16_t* __restrict__ g, const int* __restrict__ csr,
    const int* __restrict__ rp, const int* __restrict__ deg,
    const float* __restrict__ ndst, bf16_t* __restrict__ outm, int nn, int d0)
{
    int wave = threadIdx.x >> 6, lane = threadIdx.x & 63;
    int v = blockIdx.x * 4 + wave;
    if (v >= nn) return;
    int start = rp[v], cnt = deg[v];
    const int* ep = csr + start;
    int loff = d0 + (lane << 2);                // this lane's 4-element (8B) chunk of the half
    const bf16_t* base = g + loff;
    float acc[4] = {0,0,0,0};

#define SPG(j, idx) \
    int u##j = __builtin_amdgcn_readfirstlane(ep[idx]); \
    uint2 d##j = *(const uint2*)(base + (size_t)u##j * DDIM);
#define SPA(j) \
    acc[0] += bf2f(d##j.x & 0xffffu); acc[1] += bf2f(d##j.x >> 16); \
    acc[2] += bf2f(d##j.y & 0xffffu); acc[3] += bf2f(d##j.y >> 16);

    int e = 0, full8 = cnt & ~7;
    for (; e < full8; e += 8){
        SPG(0, e + 0) SPG(1, e + 1) SPG(2, e + 2) SPG(3, e + 3)
        SPG(4, e + 4) SPG(5, e + 5) SPG(6, e + 6) SPG(7, e + 7)
        SPA(0) SPA(1) SPA(2) SPA(3) SPA(4) SPA(5) SPA(6) SPA(7)
    }
    int rem = cnt - e;                          // 0..7
    if (rem){
        int cl = e + rem - 1;                   // clamp index (valid, already-hot row)
        SPG(0, e)
        SPG(1, 1 < rem ? e + 1 : cl)
        SPG(2, 2 < rem ? e + 2 : cl)
        SPG(3, 3 < rem ? e + 3 : cl)
        SPG(4, 4 < rem ? e + 4 : cl)
        SPG(5, 5 < rem ? e + 5 : cl)
        SPG(6, 6 < rem ? e + 6 : cl)
        SPA(0)
        if (rem > 1){ SPA(1) }
        if (rem > 2){ SPA(2) }
        if (rem > 3){ SPA(3) }
        if (rem > 4){ SPA(4) }
        if (rem > 5){ SPA(5) }
        if (rem > 6){ SPA(6) }
    }
#undef SPG
#undef SPA

    float s = ndst[v];
    uint2 o;
    o.x = (unsigned)f2bf(acc[0] * s) | ((unsigned)f2bf(acc[1] * s) << 16);
    o.y = (unsigned)f2bf(acc[2] * s) | ((unsigned)f2bf(acc[3] * s) << 16);
    *(uint2*)(outm + (size_t)v * DDIM + loff) = o;
}

// 40-dim SpMM for the last layer (GEMM commuted ahead of it): out = ndst*sum + b2, f32 out
// Working set: p40 = 8 MB -> already cache-resident; 8-deep unroll for MLP.

__global__ __launch_bounds__(256) void spmm40(
    const bf16_t* __restrict__ p40, const int* __restrict__ csr,
    const int* __restrict__ rp, const int* __restrict__ deg,
    const float* __restrict__ ndst, const float* __restrict__ b2,
    float* __restrict__ out, int nn)
{
    int wave = threadIdx.x >> 6, lane = threadIdx.x & 63;
    int v = blockIdx.x * 4 + wave;
    if (v >= nn || lane >= NCLS) return;
    int start = rp[v], cnt = deg[v];
    const int* ep = csr + start;
    float acc = 0.f;

#define SQG(j, idx) \
    int w##j = __builtin_amdgcn_readfirstlane(ep[idx]); \
    unsigned short t##j = p40[(size_t)w##j * NCLS + lane];
#define SQA(j) acc += bf2f((unsigned)t##j);

    int e = 0, full8 = cnt & ~7;
    for (; e < full8; e += 8){
        SQG(0, e + 0) SQG(1, e + 1) SQG(2, e + 2) SQG(3, e + 3)
        SQG(4, e + 4) SQG(5, e + 5) SQG(6, e + 6) SQG(7, e + 7)
        SQA(0) SQA(1) SQA(2) SQA(3) SQA(4) SQA(5) SQA(6) SQA(7)
    }
    int rem = cnt - e;
    if (rem){
        int cl = e + rem - 1;
        SQG(0, e)
        SQG(1, 1 < rem ? e + 1 : cl)
        SQG(2, 2 < rem ? e + 2 : cl)
        SQG(3, 3 < rem ? e + 3 : cl)
        SQG(4, 4 < rem ? e + 4 : cl)
        SQG(5, 5 < rem ? e + 5 : cl)
        SQG(6, 6 < rem ? e + 6 : cl)
        SQA(0)
        if (rem > 1){ SQA(1) }
        if (rem > 2){ SQA(2) }
        if (rem > 3){ SQA(3) }
        if (rem > 4){ SQA(4) }
        if (rem > 5){ SQA(5) }
        if (rem > 6){ SQA(6) }
    }
#undef SQG
#undef SQA

    out[(size_t)v * NCLS + lane] = acc * ndst[v] + b2[lane];
}

// ---------------- launch ----------------
// bf16 intermediates: G (d_ws, 102.4 MB) is the spmm gather source. SpMM runs as two
// sequential half-D passes; CSR fill runs as 4 dst-range passes (write locality).
// H2/P live in d_in[0] (restored pre-launch => legal scratch after its last read).

extern "C" void kernel_launch(void* const* d_in, const int* in_sizes, int n_in,
                              void* d_out, int out_size, void* d_ws, size_t ws_size,
                              hipStream_t stream)
{
    const float* feat = (const float*)d_in[0];
    const int*   src  = (const int*)d_in[1];
    const int*   dst  = (const int*)d_in[2];
    const float* Wlin = (const float*)d_in[3];
    const float* blin = (const float*)d_in[4];
    const float* W0   = (const float*)d_in[5];
    const float* b0   = (const float*)d_in[6];
    const float* W1   = (const float*)d_in[7];
    const float* b1   = (const float*)d_in[8];
    const float* W2   = (const float*)d_in[9];
    const float* b2   = (const float*)d_in[10];

    const int NN = NNODES;
    const int E  = in_sizes[1];

    char* wsp = (char*)d_ws;
    auto alloc = [&](size_t bytes) -> char* {
        char* r = wsp;
        wsp += (bytes + 255) & ~(size_t)255;
        return r;
    };
    int*    deg_out = (int*)alloc((size_t)NN * 4);
    int*    deg_in  = (int*)alloc((size_t)NN * 4);
    float*  nsrc    = (float*)alloc((size_t)NN * 4);
    float*  ndst    = (float*)alloc((size_t)NN * 4);
    int*    row_ptr = (int*)alloc((size_t)NN * 4);
    int*    cursor  = (int*)alloc((size_t)NN * 4);
    int*    bsums   = (int*)alloc(1024);
    bf16_t* WTlin   = (bf16_t*)alloc((size_t)512 * 512 * 2);
    bf16_t* WT0     = (bf16_t*)alloc((size_t)512 * 512 * 2);
    bf16_t* WT1     = (bf16_t*)alloc((size_t)512 * 512 * 2);
    bf16_t* W2T     = (bf16_t*)alloc((size_t)NCLS * 512 * 2);
    int*    csr     = (int*)alloc((size_t)E * 4);
    bf16_t* G       = (bf16_t*)alloc((size_t)NN * DDIM * 2);   // 102.4 MB

    bf16_t* H2 = (bf16_t*)d_in[0];   // feat dead after first GEMM
    bf16_t* P  = (bf16_t*)d_in[0];   // 8 MB logits scratch once H2 dead

    int eb   = (E + 255) / 256;
    int nb   = (NN + 255) / 256;
    int sb   = (NN + 1023) / 1024;
    dim3 g512((NN + 127) / 128, 4);
    dim3 g40 ((NN + 127) / 128, 1);
    int  sp  = (NN + 3) / 4;

    zero_int<<<nb, 256, 0, stream>>>(deg_out, NN);
    zero_int<<<nb, 256, 0, stream>>>(deg_in, NN);
    count_deg<<<eb, 256, 0, stream>>>(src, dst, deg_out, deg_in, E);
    norm_k<<<nb, 256, 0, stream>>>(deg_out, deg_in, nsrc, ndst, NN);

    scan_block<<<sb, 1024, 0, stream>>>(deg_in, row_ptr, bsums, NN);
    scan_block<<<1, 1024, 0, stream>>>(bsums, bsums, nullptr, sb);
    add_offs<<<sb, 1024, 0, stream>>>(row_ptr, cursor, bsums, NN);
    // 4 dst-range passes: csr window ~3.2 MB/pass stays L2-resident -> full-line writebacks
    {
        int P4 = 4, step = (NN + P4 - 1) / P4;
        for (int p = 0; p < P4; p++){
            int lo = p * step, hi = lo + step < NN ? lo + step : NN;
            fill_csr_pass<<<eb, 256, 0, stream>>>(src, dst, cursor, csr, E, lo, hi);
        }
    }

    transpose_w<<<(512 * 512 + 255) / 256, 256, 0, stream>>>(Wlin, WTlin, 512, 512);
    transpose_w<<<(512 * 512 + 255) / 256, 256, 0, stream>>>(W0, WT0, 512, 512);
    transpose_w<<<(512 * 512 + 255) / 256, 256, 0, stream>>>(W1, WT1, 512, 512);
    transpose_w<<<(512 * NCLS + 255) / 256, 256, 0, stream>>>(W2, W2T, 512, NCLS);

    // g0 = (X @ Wlin + blin) * norm_src          (feat dead after this)
    gemm_k<true ><<<g512, 256, 0, stream>>>(feat, WTlin, blin, nsrc, G, NN, 512, 0);
    // m0' = norm_dst * segsum(g0)  — two half-D passes
    spmm512h<<<sp, 256, 0, stream>>>(G, csr, row_ptr, deg_in, ndst, H2, NN, 0);
    spmm512h<<<sp, 256, 0, stream>>>(G, csr, row_ptr, deg_in, ndst, H2, NN, 256);
    // g1 = relu(m0' @ W0 + b0) * norm_src
    gemm_k<false><<<g512, 256, 0, stream>>>(H2, WT0, b0, nsrc, G, NN, 512, 1);
    // m1' = norm_dst * segsum(g1)
    spmm512h<<<sp, 256, 0, stream>>>(G, csr, row_ptr, deg_in, ndst, H2, NN, 0);
    spmm512h<<<sp, 256, 0, stream>>>(G, csr, row_ptr, deg_in, ndst, H2, NN, 256);
    // g2 = relu(m1' @ W1 + b1) * norm_src
    gemm_k<false><<<g512, 256, 0, stream>>>(H2, WT1, b1, nsrc, G, NN, 512, 1);
    // p = g2 @ W2   (GEMM commuted ahead of the final SpMM; H2 dead now)
    gemm_k<false><<<g40, 256, 0, stream>>>(G, W2T, nullptr, nullptr, P, NN, NCLS, 0);
    // out = norm_dst * segsum(p) + b2
    spmm40<<<sp, 256, 0, stream>>>(P, csr, row_ptr, deg_in, ndst, b2, (float*)d_out, NN);
}